// Round 1
// baseline (257.858 us; speedup 1.0000x reference)
//
#include <hip/hip_runtime.h>

// VQ-VAE quantizer forward, fp32 baseline.
// z: [32, 256, 32, 32] fp32; weight: [256, 1024] fp32.
// out: quantized [32*256*32*32] ++ loss [32768] ++ commitment [32768] ++ embedding [32768]

#define DTILE 16   // d-rows per B stage
#define KC    128  // codes per chunk

// wsq[k] = sum_d w[d][k]^2
__global__ void vq_wsq(const float* __restrict__ w, float* __restrict__ wsq) {
    const int k = blockIdx.x * 256 + threadIdx.x;
    float s = 0.f;
    for (int d = 0; d < 256; ++d) {
        const float v = w[(size_t)d * 1024 + k];
        s = fmaf(v, v, s);
    }
    wsq[k] = s;
}

__global__ __launch_bounds__(256, 2)
void vq_main(const float* __restrict__ z, const float* __restrict__ w,
             const float* __restrict__ wsq, float* __restrict__ out) {
    __shared__ float z_lds[256 * 64];   // [d][s]  64 KB, persistent
    __shared__ float b_lds[DTILE * KC]; // [dd][k]  8 KB, per-stage
    __shared__ int   kbest_lds[64];
    __shared__ float red_lds[4 * 64];

    const int tid = threadIdx.x;
    const int bid = blockIdx.x;
    const int b   = bid >> 4;           // 16 blocks per 1024-elem HW plane
    const int s0  = (bid & 15) * 64;    // offset within plane

    // ---- stage z tile [256][64] into LDS (coalesced float4) ----
    {
        const int lr = tid >> 4;          // 0..15
        const int lc = (tid & 15) * 4;    // 0..60
        for (int r = 0; r < 16; ++r) {
            const int d = r * 16 + lr;
            const float4 v = *reinterpret_cast<const float4*>(
                &z[(((size_t)(b * 256 + d)) << 10) + s0 + lc]);
            *reinterpret_cast<float4*>(&z_lds[d * 64 + lc]) = v;
        }
    }
    __syncthreads();

    const int ts = tid >> 4;      // s-group 0..15  (owns s = ts*4 .. +4)
    const int tk = tid & 15;      // k-group 0..15  (owns k = kbase .. +8 per chunk)
    const int sbase = ts * 4;
    const int kbase = tk * 8;

    float bestv[4] = {1e30f, 1e30f, 1e30f, 1e30f};
    int   besti[4] = {0, 0, 0, 0};

    for (int c = 0; c < 8; ++c) {
        const int k0 = c * KC;
        float acc[4][8];
        #pragma unroll
        for (int i = 0; i < 4; ++i)
            #pragma unroll
            for (int j = 0; j < 8; ++j) acc[i][j] = 0.f;

        for (int dt = 0; dt < 256; dt += DTILE) {
            __syncthreads();   // previous consumers of b_lds done
            // stage B [DTILE][KC] (coalesced float4)
            #pragma unroll
            for (int i = 0; i < 2; ++i) {
                const int idx = tid + i * 256;       // 0..511 float4 slots
                const int dd  = idx >> 5;            // 0..15
                const int kk  = (idx & 31) * 4;      // 0..124
                const float4 v = *reinterpret_cast<const float4*>(
                    &w[(size_t)(dt + dd) * 1024 + k0 + kk]);
                *reinterpret_cast<float4*>(&b_lds[dd * KC + kk]) = v;
            }
            __syncthreads();

            #pragma unroll
            for (int dd = 0; dd < DTILE; ++dd) {
                const float4 a  = *reinterpret_cast<const float4*>(
                    &z_lds[(dt + dd) * 64 + sbase]);
                const float4 b0 = *reinterpret_cast<const float4*>(
                    &b_lds[dd * KC + kbase]);
                const float4 b1 = *reinterpret_cast<const float4*>(
                    &b_lds[dd * KC + kbase + 4]);
                const float av[4] = {a.x, a.y, a.z, a.w};
                const float bv[8] = {b0.x, b0.y, b0.z, b0.w,
                                     b1.x, b1.y, b1.z, b1.w};
                #pragma unroll
                for (int i = 0; i < 4; ++i)
                    #pragma unroll
                    for (int j = 0; j < 8; ++j)
                        acc[i][j] = fmaf(av[i], bv[j], acc[i][j]);
            }
        }

        // fold chunk into running argmin (k ascending -> strict < keeps first)
        #pragma unroll
        for (int j = 0; j < 8; ++j) {
            const int k = k0 + kbase + j;
            const float wk = wsq[k];
            #pragma unroll
            for (int i = 0; i < 4; ++i) {
                const float dist = fmaf(-2.f, acc[i][j], wk);
                if (dist < bestv[i]) { bestv[i] = dist; besti[i] = k; }
            }
        }
    }

    // cross-thread argmin across the 16 tk-lanes sharing each s (same wave)
    #pragma unroll
    for (int off = 1; off < 16; off <<= 1) {
        #pragma unroll
        for (int i = 0; i < 4; ++i) {
            const float ov = __shfl_xor(bestv[i], off);
            const int   oi = __shfl_xor(besti[i], off);
            if (ov < bestv[i] || (ov == bestv[i] && oi < besti[i])) {
                bestv[i] = ov; besti[i] = oi;
            }
        }
    }
    if (tk == 0) {
        #pragma unroll
        for (int i = 0; i < 4; ++i) kbest_lds[sbase + i] = besti[i];
    }
    __syncthreads();

    // ---- epilogue: gather codes, write quantized, reduce mse ----
    const int s  = tid & 63;
    const int dg = tid >> 6;            // 0..3
    const int kb = kbest_lds[s];
    float partial = 0.f;
    for (int r = 0; r < 64; ++r) {
        const int d = dg * 64 + r;
        const float q  = w[(size_t)d * 1024 + kb];   // L2-resident gather
        const float zv = z_lds[d * 64 + s];
        const float diff = q - zv;
        partial = fmaf(diff, diff, partial);
        out[(((size_t)(b * 256 + d)) << 10) + s0 + s] = q;  // coalesced
    }
    red_lds[dg * 64 + s] = partial;
    __syncthreads();
    if (tid < 64) {
        const float m = (red_lds[s] + red_lds[64 + s] + red_lds[128 + s] +
                         red_lds[192 + s]) * (1.f / 256.f);
        const size_t n = (size_t)bid * 64 + tid;
        out[8388608 + n] = 1.25f * m;   // loss = beta*mse + mse, beta=0.25
        out[8421376 + n] = m;           // commitment
        out[8454144 + n] = m;           // embedding
    }
}

extern "C" void kernel_launch(void* const* d_in, const int* in_sizes, int n_in,
                              void* d_out, int out_size, void* d_ws, size_t ws_size,
                              hipStream_t stream) {
    const float* z = (const float*)d_in[0];
    const float* w = (const float*)d_in[1];
    float* out = (float*)d_out;
    float* wsq = (float*)d_ws;   // 1024 floats = 4 KB scratch

    vq_wsq<<<4, 256, 0, stream>>>(w, wsq);
    vq_main<<<512, 256, 0, stream>>>(z, w, wsq, out);
}

// Round 2
// 136.511 us; speedup vs baseline: 1.8889x; 1.8889x over previous
//
#include <hip/hip_runtime.h>

// VQ-VAE quantizer forward via bf16-split MFMA.
// z: [32, 256, 32, 32] fp32; weight: [256, 1024] fp32.
// out: quantized [8388608] ++ loss [32768] ++ commitment [32768] ++ embedding [32768]

typedef unsigned short ushort_t;
typedef short          s16x8  __attribute__((ext_vector_type(8)));
typedef unsigned short u16x8  __attribute__((ext_vector_type(8)));
typedef float          f32x16 __attribute__((ext_vector_type(16)));

__device__ __forceinline__ ushort_t f2bf(float x) {
    unsigned int u = __float_as_uint(x);
    u += 0x7fffu + ((u >> 16) & 1u);          // RNE
    return (ushort_t)(u >> 16);
}
__device__ __forceinline__ float bf2f(ushort_t h) {
    return __uint_as_float(((unsigned int)h) << 16);
}

// ---- prep 1: wsq[k] = sum_d w[d][k]^2 ----
__global__ void vq_wsq(const float* __restrict__ w, float* __restrict__ wsq) {
    const int k = blockIdx.x * 256 + threadIdx.x;
    float s = 0.f;
    for (int d = 0; d < 256; ++d) {
        const float v = w[(size_t)d * 1024 + k];
        s = fmaf(v, v, s);
    }
    wsq[k] = s;
}

// ---- prep 2: transpose + bf16-split W -> wt_hi/wt_lo [1024 k][256 d] ----
__global__ void vq_wprep(const float* __restrict__ w,
                         ushort_t* __restrict__ wt_hi, ushort_t* __restrict__ wt_lo) {
    __shared__ float tile[64][65];
    const int t  = threadIdx.x;
    const int kt = blockIdx.x & 15;
    const int dt = blockIdx.x >> 4;
    for (int i = 0; i < 16; ++i) {
        const int lin = t + 256 * i;
        const int dd = lin >> 6, kk = lin & 63;
        tile[kk][dd] = w[(size_t)(dt * 64 + dd) * 1024 + kt * 64 + kk];
    }
    __syncthreads();
    for (int i = 0; i < 16; ++i) {
        const int lin = t + 256 * i;
        const int kk = lin >> 6, dd = lin & 63;
        const float v = tile[kk][dd];
        const ushort_t hb = f2bf(v);
        const ushort_t lb = f2bf(v - bf2f(hb));
        const size_t o = (size_t)(kt * 64 + kk) * 256 + dt * 64 + dd;
        wt_hi[o] = hb;
        wt_lo[o] = lb;
    }
}

// ---- main ----
__global__ __launch_bounds__(256, 1)
void vq_mfma(const float* __restrict__ z,
             const ushort_t* __restrict__ wt_hi, const ushort_t* __restrict__ wt_lo,
             const float* __restrict__ wsq, float* __restrict__ out) {
    __shared__ ushort_t z_hi[64][264];          // [n][d] padded
    __shared__ ushort_t z_lo[64][264];
    __shared__ ushort_t wl_hi[2][256][40];      // [buf][k][32d + pad]
    __shared__ ushort_t wl_lo[2][256][40];
    __shared__ float    wred_v[4][64];
    __shared__ int      wred_i[4][64];
    __shared__ int      kbest[64];
    __shared__ float    red[256];

    const int tid  = threadIdx.x;
    const int bid  = blockIdx.x;
    const int b    = bid >> 4;
    const int s0   = (bid & 15) * 64;
    const int lane = tid & 63;
    const int wk   = tid >> 6;      // wave id -> k-quarter of chunk
    const int l31  = lane & 31;
    const int lhi  = lane >> 5;

    // ---- prefetch W stage (c=0, dt=0) into registers ----
    u16x8 pr_h[4], pr_l[4];
    #pragma unroll
    for (int i = 0; i < 4; ++i) {
        const int lin = tid + 256 * i;
        const int k = lin >> 2, ch = lin & 3;
        const size_t o = (size_t)k * 256 + ch * 8;
        pr_h[i] = *reinterpret_cast<const u16x8*>(&wt_hi[o]);
        pr_l[i] = *reinterpret_cast<const u16x8*>(&wt_lo[o]);
    }

    // ---- stage z: [b][d][hw] -> z_hi/z_lo [n][d] ----
    {
        const int dr = tid >> 4;
        const int sc = (tid & 15) * 4;
        for (int it = 0; it < 16; ++it) {
            const int d = it * 16 + dr;
            const float4 v = *reinterpret_cast<const float4*>(
                &z[(((size_t)(b * 256 + d)) << 10) + s0 + sc]);
            const float vv[4] = {v.x, v.y, v.z, v.w};
            #pragma unroll
            for (int j = 0; j < 4; ++j) {
                const ushort_t hb = f2bf(vv[j]);
                const ushort_t lb = f2bf(vv[j] - bf2f(hb));
                z_hi[sc + j][d] = hb;
                z_lo[sc + j][d] = lb;
            }
        }
    }
    __syncthreads();

    // ---- A_hi fragments -> registers (row = m*32+l31, d = j*16 + lhi*8 + i) ----
    s16x8 a_hi[2][16];
    #pragma unroll
    for (int m = 0; m < 2; ++m)
        #pragma unroll
        for (int j = 0; j < 16; ++j)
            a_hi[m][j] = *reinterpret_cast<const s16x8*>(&z_hi[m * 32 + l31][j * 16 + lhi * 8]);

    // ---- write stage 0 ----
    #pragma unroll
    for (int i = 0; i < 4; ++i) {
        const int lin = tid + 256 * i;
        const int k = lin >> 2, ch = lin & 3;
        *reinterpret_cast<u16x8*>(&wl_hi[0][k][ch * 8]) = pr_h[i];
        *reinterpret_cast<u16x8*>(&wl_lo[0][k][ch * 8]) = pr_l[i];
    }
    __syncthreads();

    float bestv[2][16];
    int   besti[2][16];
    #pragma unroll
    for (int m = 0; m < 2; ++m)
        #pragma unroll
        for (int r = 0; r < 16; ++r) { bestv[m][r] = 1e30f; besti[m][r] = 0; }

    for (int c = 0; c < 4; ++c) {           // k-chunks of 256
        f32x16 acc[2][2];
        #pragma unroll
        for (int m = 0; m < 2; ++m)
            #pragma unroll
            for (int nt = 0; nt < 2; ++nt)
                #pragma unroll
                for (int e = 0; e < 16; ++e) acc[m][nt][e] = 0.f;

        #pragma unroll
        for (int dt = 0; dt < 8; ++dt) {    // 32-d stages
            const int buf  = dt & 1;        // (c*8+dt)&1 == dt&1
            const bool last = (c == 3) && (dt == 7);

            // prefetch next stage (global -> regs), hidden under MFMA
            if (!last) {
                const int ndt = (dt + 1) & 7;
                const int nc  = (dt == 7) ? c + 1 : c;
                #pragma unroll
                for (int i = 0; i < 4; ++i) {
                    const int lin = tid + 256 * i;
                    const int k = lin >> 2, ch = lin & 3;
                    const size_t o = (size_t)(nc * 256 + k) * 256 + ndt * 32 + ch * 8;
                    pr_h[i] = *reinterpret_cast<const u16x8*>(&wt_hi[o]);
                    pr_l[i] = *reinterpret_cast<const u16x8*>(&wt_lo[o]);
                }
            }

            // compute this stage: 2 d-steps of 16
            #pragma unroll
            for (int ds = 0; ds < 2; ++ds) {
                const int j = dt * 2 + ds;          // global d-step
                const int dloc = ds * 16 + lhi * 8; // within staged window
                s16x8 al[2];
                #pragma unroll
                for (int m = 0; m < 2; ++m)
                    al[m] = *reinterpret_cast<const s16x8*>(
                        &z_lo[m * 32 + l31][j * 16 + lhi * 8]);
                #pragma unroll
                for (int nt = 0; nt < 2; ++nt) {
                    const int krow = wk * 64 + nt * 32 + l31;
                    const s16x8 bh = *reinterpret_cast<const s16x8*>(&wl_hi[buf][krow][dloc]);
                    const s16x8 bl = *reinterpret_cast<const s16x8*>(&wl_lo[buf][krow][dloc]);
                    #pragma unroll
                    for (int m = 0; m < 2; ++m) {
                        acc[m][nt] = __builtin_amdgcn_mfma_f32_32x32x16_bf16(
                            a_hi[m][j], bh, acc[m][nt], 0, 0, 0);
                        acc[m][nt] = __builtin_amdgcn_mfma_f32_32x32x16_bf16(
                            a_hi[m][j], bl, acc[m][nt], 0, 0, 0);
                        acc[m][nt] = __builtin_amdgcn_mfma_f32_32x32x16_bf16(
                            al[m],     bh, acc[m][nt], 0, 0, 0);
                    }
                }
            }

            // fold chunk into running argmin after its last stage
            if (dt == 7) {
                #pragma unroll
                for (int nt = 0; nt < 2; ++nt) {
                    const int kcol = c * 256 + wk * 64 + nt * 32 + l31;
                    const float wq = wsq[kcol];
                    #pragma unroll
                    for (int m = 0; m < 2; ++m)
                        #pragma unroll
                        for (int r = 0; r < 16; ++r) {
                            const float dist = fmaf(-2.f, acc[m][nt][r], wq);
                            if (dist < bestv[m][r]) { bestv[m][r] = dist; besti[m][r] = kcol; }
                        }
                }
            }

            // write next stage to the other buffer
            if (!last) {
                const int nbuf = buf ^ 1;
                #pragma unroll
                for (int i = 0; i < 4; ++i) {
                    const int lin = tid + 256 * i;
                    const int k = lin >> 2, ch = lin & 3;
                    *reinterpret_cast<u16x8*>(&wl_hi[nbuf][k][ch * 8]) = pr_h[i];
                    *reinterpret_cast<u16x8*>(&wl_lo[nbuf][k][ch * 8]) = pr_l[i];
                }
            }
            __syncthreads();
        }
    }

    // ---- in-wave argmin across the 32 k-lanes (rows identical across l31) ----
    #pragma unroll
    for (int off = 1; off < 32; off <<= 1) {
        #pragma unroll
        for (int m = 0; m < 2; ++m)
            #pragma unroll
            for (int r = 0; r < 16; ++r) {
                const float ov = __shfl_xor(bestv[m][r], off);
                const int   oi = __shfl_xor(besti[m][r], off);
                if (ov < bestv[m][r] || (ov == bestv[m][r] && oi < besti[m][r])) {
                    bestv[m][r] = ov; besti[m][r] = oi;
                }
            }
    }
    if (l31 == 0) {
        #pragma unroll
        for (int m = 0; m < 2; ++m)
            #pragma unroll
            for (int r = 0; r < 16; ++r) {
                const int n = m * 32 + (r & 3) + 8 * (r >> 2) + 4 * lhi;
                wred_v[wk][n] = bestv[m][r];
                wred_i[wk][n] = besti[m][r];
            }
    }
    __syncthreads();
    if (tid < 64) {
        float v = wred_v[0][tid];
        int   i0 = wred_i[0][tid];
        #pragma unroll
        for (int wv = 1; wv < 4; ++wv) {
            const float ov = wred_v[wv][tid];
            const int   oi = wred_i[wv][tid];
            if (ov < v || (ov == v && oi < i0)) { v = ov; i0 = oi; }
        }
        kbest[tid] = i0;
    }
    __syncthreads();

    // ---- epilogue: gather code row, write quantized, reduce mse ----
    const int es = tid & 63;
    const int dg = tid >> 6;
    const int kb = kbest[es];
    float partial = 0.f;
    #pragma unroll
    for (int r8 = 0; r8 < 8; ++r8) {
        const int dbase = dg * 64 + r8 * 8;
        const u16x8 zh = *reinterpret_cast<const u16x8*>(&z_hi[es][dbase]);
        const u16x8 zl = *reinterpret_cast<const u16x8*>(&z_lo[es][dbase]);
        const u16x8 qh = *reinterpret_cast<const u16x8*>(&wt_hi[(size_t)kb * 256 + dbase]);
        const u16x8 ql = *reinterpret_cast<const u16x8*>(&wt_lo[(size_t)kb * 256 + dbase]);
        #pragma unroll
        for (int jj = 0; jj < 8; ++jj) {
            const int d = dbase + jj;
            const float zv = bf2f(zh[jj]) + bf2f(zl[jj]);
            const float q  = bf2f(qh[jj]) + bf2f(ql[jj]);
            const float diff = q - zv;
            partial = fmaf(diff, diff, partial);
            out[(((size_t)(b * 256 + d)) << 10) + s0 + es] = q;
        }
    }
    red[tid] = partial;
    __syncthreads();
    if (tid < 64) {
        const float m = (red[tid] + red[64 + tid] + red[128 + tid] + red[192 + tid])
                        * (1.f / 256.f);
        const size_t n = (size_t)bid * 64 + tid;
        out[8388608 + n] = 1.25f * m;   // loss = (beta=0.25)*mse + mse
        out[8421376 + n] = m;           // commitment
        out[8454144 + n] = m;           // embedding
    }
}

extern "C" void kernel_launch(void* const* d_in, const int* in_sizes, int n_in,
                              void* d_out, int out_size, void* d_ws, size_t ws_size,
                              hipStream_t stream) {
    const float* z = (const float*)d_in[0];
    const float* w = (const float*)d_in[1];
    float* out = (float*)d_out;

    float*    wsq   = (float*)d_ws;                              // 4 KB
    ushort_t* wt_hi = (ushort_t*)((char*)d_ws + 4096);           // 512 KB
    ushort_t* wt_lo = (ushort_t*)((char*)d_ws + 4096 + 524288);  // 512 KB

    vq_wsq  <<<4,   256, 0, stream>>>(w, wsq);
    vq_wprep<<<64,  256, 0, stream>>>(w, wt_hi, wt_lo);
    vq_mfma <<<512, 256, 0, stream>>>(z, wt_hi, wt_lo, wsq, out);
}

// Round 3
// 107.704 us; speedup vs baseline: 2.3941x; 1.2675x over previous
//
#include <hip/hip_runtime.h>

// VQ-VAE quantizer forward via bf16-split MFMA (2-term: zh*(wh+wl)).
// z: [32, 256, 32, 32] fp32; weight: [256, 1024] fp32.
// out: quantized [8388608] ++ loss [32768] ++ commitment [32768] ++ embedding [32768]

typedef unsigned short ushort_t;
typedef short          s16x8  __attribute__((ext_vector_type(8)));
typedef unsigned short u16x8  __attribute__((ext_vector_type(8)));
typedef float          f32x16 __attribute__((ext_vector_type(16)));

__device__ __forceinline__ ushort_t f2bf(float x) {
    unsigned int u = __float_as_uint(x);
    u += 0x7fffu + ((u >> 16) & 1u);          // RNE
    return (ushort_t)(u >> 16);
}
__device__ __forceinline__ float bf2f(ushort_t h) {
    return __uint_as_float(((unsigned int)h) << 16);
}

// ---- prep 1: wsq[k] = sum_d w[d][k]^2 (exact fp32) ----
__global__ void vq_wsq(const float* __restrict__ w, float* __restrict__ wsq) {
    const int k = blockIdx.x * 256 + threadIdx.x;
    float s = 0.f;
    for (int d = 0; d < 256; ++d) {
        const float v = w[(size_t)d * 1024 + k];
        s = fmaf(v, v, s);
    }
    wsq[k] = s;
}

// ---- prep 2: transpose + bf16-split W into stage-major slabs ----
// slab layout: off(d,k) = (d>>5)*32768 + k*32 + (d&31)   [8 slabs of 1024k x 32d]
__global__ void vq_wprep(const float* __restrict__ w,
                         ushort_t* __restrict__ hi, ushort_t* __restrict__ lo) {
    __shared__ float tile[64][65];
    const int t   = threadIdx.x;
    const int kt  = blockIdx.x & 15;
    const int dt6 = blockIdx.x >> 4;
    for (int i = 0; i < 16; ++i) {
        const int lin = t + 256 * i;
        const int dd = lin >> 6, kk = lin & 63;
        tile[kk][dd] = w[(size_t)(dt6 * 64 + dd) * 1024 + kt * 64 + kk];
    }
    __syncthreads();
    for (int i = 0; i < 16; ++i) {
        const int lin = t + 256 * i;
        const int kk = lin >> 6, ddl = lin & 63;
        const int d = dt6 * 64 + ddl, k = kt * 64 + kk;
        const float v = tile[kk][ddl];
        const ushort_t hb = f2bf(v);
        const ushort_t lb = f2bf(v - bf2f(hb));
        const size_t o = (size_t)(d >> 5) * 32768 + (size_t)k * 32 + (d & 31);
        hi[o] = hb;
        lo[o] = lb;
    }
}

// ---- main ----
__global__ __launch_bounds__(256, 2)
void vq_mfma(const float* __restrict__ z,
             const ushort_t* __restrict__ wh_slab, const ushort_t* __restrict__ wl_slab,
             const float* __restrict__ wsq, float* __restrict__ out) {
    __shared__ ushort_t z_hi[64][264];      // [n][d]  33.8 KB
    __shared__ ushort_t wl_h[256][40];      // [k][32d + pad]  20 KB
    __shared__ ushort_t wl_l[256][40];      // 20 KB
    __shared__ float    wred_v[4][64];
    __shared__ int      wred_i[4][64];
    __shared__ int      kbest[64];
    __shared__ float    red[256];

    const int tid  = threadIdx.x;
    const int bid  = blockIdx.x;
    const int b    = bid >> 4;
    const int s0   = (bid & 15) * 64;
    const int lane = tid & 63;
    const int wk   = tid >> 6;      // wave id -> k-quarter of each 256-chunk
    const int l31  = lane & 31;
    const int lhi  = lane >> 5;

    // ---- prefetch W stage (c=0,dt=0) into registers (in flight during z staging) ----
    u16x8 ph[4], pl[4];
    #pragma unroll
    for (int i = 0; i < 4; ++i) {
        const int chunk = i * 256 + tid;            // 1024 u16x8 chunks per stage
        ph[i] = *reinterpret_cast<const u16x8*>(&wh_slab[(size_t)chunk * 8]);
        pl[i] = *reinterpret_cast<const u16x8*>(&wl_slab[(size_t)chunk * 8]);
    }

    // ---- stage z -> z_hi [n][d] (coalesced reads; j staggered to spread write banks) ----
    {
        const int u  = tid & 15;      // s-group
        const int sc = u * 4;
        const int dr = tid >> 4;      // 0..15
        for (int it = 0; it < 16; ++it) {
            const int d = it * 16 + dr;
            const float4 v = *reinterpret_cast<const float4*>(
                &z[(((size_t)(b * 256 + d)) << 10) + s0 + sc]);
            const float vv[4] = {v.x, v.y, v.z, v.w};
            #pragma unroll
            for (int jj = 0; jj < 4; ++jj) {
                const int j = (jj + u) & 3;
                z_hi[sc + j][d] = f2bf(vv[j]);
            }
        }
    }
    __syncthreads();

    // ---- A fragments -> registers (row = m*32+l31, d = j*16 + lhi*8 + e) ----
    s16x8 a_hi[2][16];
    #pragma unroll
    for (int m = 0; m < 2; ++m)
        #pragma unroll
        for (int j = 0; j < 16; ++j)
            a_hi[m][j] = *reinterpret_cast<const s16x8*>(&z_hi[m * 32 + l31][j * 16 + lhi * 8]);

    float bestv[2][16];
    int   besti[2][16];
    #pragma unroll
    for (int m = 0; m < 2; ++m)
        #pragma unroll
        for (int r = 0; r < 16; ++r) { bestv[m][r] = 1e30f; besti[m][r] = 0; }

    for (int c = 0; c < 4; ++c) {           // k-chunks of 256
        f32x16 acc[2][2];
        #pragma unroll
        for (int m = 0; m < 2; ++m)
            #pragma unroll
            for (int nt = 0; nt < 2; ++nt)
                #pragma unroll
                for (int e = 0; e < 16; ++e) acc[m][nt][e] = 0.f;

        #pragma unroll
        for (int dt = 0; dt < 8; ++dt) {    // 32-d stages
            __syncthreads();                // previous stage's readers done

            // write this stage (regs -> LDS)
            #pragma unroll
            for (int i = 0; i < 4; ++i) {
                const int chunk = i * 256 + tid;
                const int k = chunk >> 2, part = chunk & 3;
                *reinterpret_cast<u16x8*>(&wl_h[k][part * 8]) = ph[i];
                *reinterpret_cast<u16x8*>(&wl_l[k][part * 8]) = pl[i];
            }

            // issue next stage's global loads (land during compute)
            if (!(c == 3 && dt == 7)) {
                const int ndt = (dt + 1) & 7;
                const int nc  = (dt == 7) ? c + 1 : c;
                const size_t base = (size_t)ndt * 32768 + (size_t)nc * 8192;
                #pragma unroll
                for (int i = 0; i < 4; ++i) {
                    const int chunk = i * 256 + tid;
                    ph[i] = *reinterpret_cast<const u16x8*>(&wh_slab[base + (size_t)chunk * 8]);
                    pl[i] = *reinterpret_cast<const u16x8*>(&wl_slab[base + (size_t)chunk * 8]);
                }
            }
            __syncthreads();                // stage visible

            __builtin_amdgcn_s_setprio(1);
            #pragma unroll
            for (int ds = 0; ds < 2; ++ds) {
                const int j    = dt * 2 + ds;
                const int dloc = ds * 16 + lhi * 8;
                #pragma unroll
                for (int nt = 0; nt < 2; ++nt) {
                    const int krow = wk * 64 + nt * 32 + l31;
                    const s16x8 bh = *reinterpret_cast<const s16x8*>(&wl_h[krow][dloc]);
                    const s16x8 bl = *reinterpret_cast<const s16x8*>(&wl_l[krow][dloc]);
                    #pragma unroll
                    for (int m = 0; m < 2; ++m) {
                        acc[m][nt] = __builtin_amdgcn_mfma_f32_32x32x16_bf16(
                            a_hi[m][j], bh, acc[m][nt], 0, 0, 0);
                        acc[m][nt] = __builtin_amdgcn_mfma_f32_32x32x16_bf16(
                            a_hi[m][j], bl, acc[m][nt], 0, 0, 0);
                    }
                }
            }
            __builtin_amdgcn_s_setprio(0);
        }

        // fold chunk into running argmin
        #pragma unroll
        for (int nt = 0; nt < 2; ++nt) {
            const int kcol = c * 256 + wk * 64 + nt * 32 + l31;
            const float wq = wsq[kcol];
            #pragma unroll
            for (int m = 0; m < 2; ++m)
                #pragma unroll
                for (int r = 0; r < 16; ++r) {
                    const float dist = fmaf(-2.f, acc[m][nt][r], wq);
                    if (dist < bestv[m][r]) { bestv[m][r] = dist; besti[m][r] = kcol; }
                }
        }
    }

    // ---- in-wave argmin across the 32 k-lanes ----
    #pragma unroll
    for (int off = 1; off < 32; off <<= 1) {
        #pragma unroll
        for (int m = 0; m < 2; ++m)
            #pragma unroll
            for (int r = 0; r < 16; ++r) {
                const float ov = __shfl_xor(bestv[m][r], off);
                const int   oi = __shfl_xor(besti[m][r], off);
                if (ov < bestv[m][r] || (ov == bestv[m][r] && oi < besti[m][r])) {
                    bestv[m][r] = ov; besti[m][r] = oi;
                }
            }
    }
    if (l31 == 0) {
        #pragma unroll
        for (int m = 0; m < 2; ++m)
            #pragma unroll
            for (int r = 0; r < 16; ++r) {
                const int n = m * 32 + (r & 3) + 8 * (r >> 2) + 4 * lhi;
                wred_v[wk][n] = bestv[m][r];
                wred_i[wk][n] = besti[m][r];
            }
    }
    __syncthreads();
    if (tid < 64) {
        float v = wred_v[0][tid];
        int   i0 = wred_i[0][tid];
        #pragma unroll
        for (int wv = 1; wv < 4; ++wv) {
            const float ov = wred_v[wv][tid];
            const int   oi = wred_i[wv][tid];
            if (ov < v || (ov == v && oi < i0)) { v = ov; i0 = oi; }
        }
        kbest[tid] = i0;
    }
    __syncthreads();

    // ---- epilogue: gather code, write quantized, mse from accurate fp32 z ----
    const int es = tid & 63;
    const int dg = tid >> 6;            // 0..3 -> d-range dg*64..+63
    const int kb = kbest[es];
    float partial = 0.f;
    #pragma unroll
    for (int si = 0; si < 2; ++si) {
        const int dt = dg * 2 + si;     // slab index
        const size_t base = (size_t)dt * 32768 + (size_t)kb * 32;
        #pragma unroll
        for (int part = 0; part < 4; ++part) {
            const u16x8 qh = *reinterpret_cast<const u16x8*>(&wh_slab[base + part * 8]);
            const u16x8 ql = *reinterpret_cast<const u16x8*>(&wl_slab[base + part * 8]);
            #pragma unroll
            for (int e = 0; e < 8; ++e) {
                const int d = dt * 32 + part * 8 + e;
                const float q  = bf2f(qh[e]) + bf2f(ql[e]);
                const float zv = z[(((size_t)(b * 256 + d)) << 10) + s0 + es];
                const float diff = q - zv;
                partial = fmaf(diff, diff, partial);
                out[(((size_t)(b * 256 + d)) << 10) + s0 + es] = q;
            }
        }
    }
    red[tid] = partial;
    __syncthreads();
    if (tid < 64) {
        const float m = (red[tid] + red[64 + tid] + red[128 + tid] + red[192 + tid])
                        * (1.f / 256.f);
        const size_t n = (size_t)bid * 64 + tid;
        out[8388608 + n] = 1.25f * m;   // loss = (beta=0.25)*mse + mse
        out[8421376 + n] = m;           // commitment
        out[8454144 + n] = m;           // embedding
    }
}

extern "C" void kernel_launch(void* const* d_in, const int* in_sizes, int n_in,
                              void* d_out, int out_size, void* d_ws, size_t ws_size,
                              hipStream_t stream) {
    const float* z = (const float*)d_in[0];
    const float* w = (const float*)d_in[1];
    float* out = (float*)d_out;

    float*    wsq     = (float*)d_ws;                              // 4 KB
    ushort_t* wh_slab = (ushort_t*)((char*)d_ws + 4096);           // 512 KB
    ushort_t* wl_slab = (ushort_t*)((char*)d_ws + 4096 + 524288);  // 512 KB

    vq_wsq  <<<4,   256, 0, stream>>>(w, wsq);
    vq_wprep<<<64,  256, 0, stream>>>(w, wh_slab, wl_slab);
    vq_mfma <<<512, 256, 0, stream>>>(z, wh_slab, wl_slab, wsq, out);
}

// Round 4
// 75.899 us; speedup vs baseline: 3.3974x; 1.4190x over previous
//
#include <hip/hip_runtime.h>

// VQ-VAE quantizer forward. Scores via 1-term bf16 MFMA (zh*wh), B fragments
// loaded directly global->reg (no LDS staging, no main-loop barriers),
// mse recovered from the score accumulator (z read exactly once).
// z: [32, 256, 32, 32] fp32; weight: [256, 1024] fp32.
// out: quantized [8388608] ++ loss [32768] ++ commitment [32768] ++ embedding [32768]

typedef unsigned short ushort_t;
typedef short          s16x8  __attribute__((ext_vector_type(8)));
typedef float          f32x16 __attribute__((ext_vector_type(16)));

__device__ __forceinline__ ushort_t f2bf(float x) {
    unsigned int u = __float_as_uint(x);
    u += 0x7fffu + ((u >> 16) & 1u);          // RNE
    return (ushort_t)(u >> 16);
}
__device__ __forceinline__ float bf2f(ushort_t h) {
    return __uint_as_float(((unsigned int)h) << 16);
}

// ---- prep: transpose + bf16-split W into k-major slabs + wsq, one kernel ----
// slab layout: off(d,k) = (d>>5)*32768 + k*32 + (d&31)   [8 slabs of 1024k x 32d]
__global__ __launch_bounds__(256)
void vq_wprep(const float* __restrict__ w,
              ushort_t* __restrict__ hi, ushort_t* __restrict__ lo,
              float* __restrict__ wsq) {
    __shared__ float tile[64][65];
    __shared__ float psum[64][4];
    const int t  = threadIdx.x;
    const int kt = blockIdx.x;          // 16 blocks, 64 codes each
    const int kk = t >> 2;              // k-local 0..63
    const int dq = t & 3;               // d-quarter within 32-d slab
    float acc = 0.f;
    for (int dt6 = 0; dt6 < 4; ++dt6) {
        __syncthreads();
        #pragma unroll
        for (int i = 0; i < 16; ++i) {
            const int lin = t + 256 * i;
            const int dd = lin >> 6, k2 = lin & 63;
            tile[dd][k2] = w[(size_t)(dt6 * 64 + dd) * 1024 + kt * 64 + k2];
        }
        __syncthreads();
        #pragma unroll
        for (int half = 0; half < 2; ++half) {
            s16x8 hv, lv;
            #pragma unroll
            for (int e = 0; e < 8; ++e) {
                const int dd = half * 32 + dq * 8 + e;
                const float v = tile[dd][kk];
                const ushort_t hb = f2bf(v);
                hv[e] = (short)hb;
                lv[e] = (short)f2bf(v - bf2f(hb));
                acc = fmaf(v, v, acc);
            }
            const size_t base = (size_t)(dt6 * 2 + half) * 32768
                              + (size_t)(kt * 64 + kk) * 32 + dq * 8;
            *reinterpret_cast<s16x8*>(&hi[base]) = hv;
            *reinterpret_cast<s16x8*>(&lo[base]) = lv;
        }
    }
    psum[kk][dq] = acc;
    __syncthreads();
    if (t < 64)
        wsq[kt * 64 + t] = psum[t][0] + psum[t][1] + psum[t][2] + psum[t][3];
}

// ---- main ----
__global__ __launch_bounds__(256, 2)
void vq_mfma(const float* __restrict__ z,
             const ushort_t* __restrict__ wh_slab, const ushort_t* __restrict__ wl_slab,
             const float* __restrict__ wsq, float* __restrict__ out) {
    __shared__ ushort_t z_hi[64][264];      // [n][d] padded, 33.8 KB
    __shared__ float    psum[16][64];       // z^2 partials [dr][s]
    __shared__ float    wred_v[4][64];
    __shared__ int      wred_i[4][64];
    __shared__ int      kbest[64];

    const int tid  = threadIdx.x;
    const int bid  = blockIdx.x;
    const int b    = bid >> 4;
    const int s0   = (bid & 15) * 64;
    const int lane = tid & 63;
    const int wk   = tid >> 6;      // wave id -> k-quarter of each 256-chunk
    const int l31  = lane & 31;
    const int lhi  = lane >> 5;

    // ---- stage z -> z_hi [n][d] + per-thread z^2 partials (z read ONCE) ----
    {
        const int u  = tid & 15;
        const int sc = u * 4;
        const int dr = tid >> 4;      // 0..15
        float p[4] = {0.f, 0.f, 0.f, 0.f};
        for (int it = 0; it < 16; ++it) {
            const int d = it * 16 + dr;
            const float4 v = *reinterpret_cast<const float4*>(
                &z[(((size_t)(b * 256 + d)) << 10) + s0 + sc]);
            const float vv[4] = {v.x, v.y, v.z, v.w};
            #pragma unroll
            for (int jj = 0; jj < 4; ++jj) {
                const int j = (jj + u) & 3;           // stagger write banks
                z_hi[sc + j][d] = f2bf(vv[j]);
                p[j] = fmaf(vv[j], vv[j], p[j]);
            }
        }
        #pragma unroll
        for (int j = 0; j < 4; ++j) psum[dr][sc + j] = p[j];
    }
    __syncthreads();

    // ---- A fragments -> registers (row = m*32+l31, d = j*16 + lhi*8 + e) ----
    s16x8 a[2][16];
    #pragma unroll
    for (int m = 0; m < 2; ++m)
        #pragma unroll
        for (int j = 0; j < 16; ++j)
            a[m][j] = *reinterpret_cast<const s16x8*>(&z_hi[m * 32 + l31][j * 16 + lhi * 8]);

    float bestv[2][16];
    int   besti[2][16];
    #pragma unroll
    for (int m = 0; m < 2; ++m)
        #pragma unroll
        for (int r = 0; r < 16; ++r) { bestv[m][r] = 1e30f; besti[m][r] = 0; }

    for (int c = 0; c < 4; ++c) {           // k-chunks of 256
        f32x16 acc[2][2];
        #pragma unroll
        for (int m = 0; m < 2; ++m)
            #pragma unroll
            for (int nt = 0; nt < 2; ++nt)
                #pragma unroll
                for (int e = 0; e < 16; ++e) acc[m][nt][e] = 0.f;

        const size_t kb0 = (size_t)(c * 256 + wk * 64 + l31) * 32 + lhi * 8;
        const size_t kb1 = kb0 + 32 * 32;

        // register pipeline, depth 2 (j and j+1 in flight)
        s16x8 bb[2][2];
        #pragma unroll
        for (int jj = 0; jj < 2; ++jj) {
            bb[jj][0] = *reinterpret_cast<const s16x8*>(&wh_slab[(jj & 1) * 16 + kb0]);
            bb[jj][1] = *reinterpret_cast<const s16x8*>(&wh_slab[(jj & 1) * 16 + kb1]);
        }

        #pragma unroll
        for (int j = 0; j < 16; ++j) {
            #pragma unroll
            for (int nt = 0; nt < 2; ++nt)
                #pragma unroll
                for (int m = 0; m < 2; ++m)
                    acc[m][nt] = __builtin_amdgcn_mfma_f32_32x32x16_bf16(
                        a[m][j], bb[j & 1][nt], acc[m][nt], 0, 0, 0);
            if (j + 2 < 16) {
                const size_t base = (size_t)((j + 2) >> 1) * 32768 + ((j + 2) & 1) * 16;
                bb[j & 1][0] = *reinterpret_cast<const s16x8*>(&wh_slab[base + kb0]);
                bb[j & 1][1] = *reinterpret_cast<const s16x8*>(&wh_slab[base + kb1]);
            }
        }

        // fold chunk into running argmin (dist = wsq - 2*score)
        #pragma unroll
        for (int nt = 0; nt < 2; ++nt) {
            const int kcol = c * 256 + wk * 64 + nt * 32 + l31;
            const float wq = wsq[kcol];
            #pragma unroll
            for (int m = 0; m < 2; ++m)
                #pragma unroll
                for (int r = 0; r < 16; ++r) {
                    const float dist = fmaf(-2.f, acc[m][nt][r], wq);
                    if (dist < bestv[m][r]) { bestv[m][r] = dist; besti[m][r] = kcol; }
                }
        }
    }

    // ---- in-wave argmin across the 32 k-lanes ----
    #pragma unroll
    for (int off = 1; off < 32; off <<= 1) {
        #pragma unroll
        for (int m = 0; m < 2; ++m)
            #pragma unroll
            for (int r = 0; r < 16; ++r) {
                const float ov = __shfl_xor(bestv[m][r], off);
                const int   oi = __shfl_xor(besti[m][r], off);
                if (ov < bestv[m][r] || (ov == bestv[m][r] && oi < besti[m][r])) {
                    bestv[m][r] = ov; besti[m][r] = oi;
                }
            }
    }
    if (l31 == 0) {
        #pragma unroll
        for (int m = 0; m < 2; ++m)
            #pragma unroll
            for (int r = 0; r < 16; ++r) {
                const int n = m * 32 + (r & 3) + 8 * (r >> 2) + 4 * lhi;
                wred_v[wk][n] = bestv[m][r];
                wred_i[wk][n] = besti[m][r];
            }
    }
    __syncthreads();

    // ---- final per-row reduce + loss outputs (mse from score accumulator) ----
    if (tid < 64) {
        float v  = wred_v[0][tid];
        int   i0 = wred_i[0][tid];
        #pragma unroll
        for (int wv = 1; wv < 4; ++wv) {
            const float ov = wred_v[wv][tid];
            const int   oi = wred_i[wv][tid];
            if (ov < v || (ov == v && oi < i0)) { v = ov; i0 = oi; }
        }
        kbest[tid] = i0;
        float zs = 0.f;
        #pragma unroll
        for (int r = 0; r < 16; ++r) zs += psum[r][tid];
        const float mse = (zs + v) * (1.f / 256.f);   // zsq - 2*score + wsq
        const size_t n = (size_t)bid * 64 + tid;
        out[8388608 + n] = 1.25f * mse;   // loss = (beta=0.25)*mse + mse
        out[8421376 + n] = mse;           // commitment
        out[8454144 + n] = mse;           // embedding
    }
    __syncthreads();

    // ---- quantized epilogue: gather hi+lo code rows, coalesced writes ----
    const int es = tid & 63;
    const int dg = tid >> 6;            // 0..3 -> d-range dg*64..+63
    const int kb = kbest[es];
    #pragma unroll
    for (int si = 0; si < 2; ++si) {
        const int dt = dg * 2 + si;     // slab index
        const size_t base = (size_t)dt * 32768 + (size_t)kb * 32;
        #pragma unroll
        for (int part = 0; part < 4; ++part) {
            const s16x8 qh = *reinterpret_cast<const s16x8*>(&wh_slab[base + part * 8]);
            const s16x8 ql = *reinterpret_cast<const s16x8*>(&wl_slab[base + part * 8]);
            #pragma unroll
            for (int e = 0; e < 8; ++e) {
                const int d = dt * 32 + part * 8 + e;
                const float q = bf2f((ushort_t)qh[e]) + bf2f((ushort_t)ql[e]);
                out[(((size_t)(b * 256 + d)) << 10) + s0 + es] = q;
            }
        }
    }
}

extern "C" void kernel_launch(void* const* d_in, const int* in_sizes, int n_in,
                              void* d_out, int out_size, void* d_ws, size_t ws_size,
                              hipStream_t stream) {
    const float* z = (const float*)d_in[0];
    const float* w = (const float*)d_in[1];
    float* out = (float*)d_out;

    float*    wsq     = (float*)d_ws;                              // 4 KB
    ushort_t* wh_slab = (ushort_t*)((char*)d_ws + 4096);           // 512 KB
    ushort_t* wl_slab = (ushort_t*)((char*)d_ws + 4096 + 524288);  // 512 KB

    vq_wprep<<<16,  256, 0, stream>>>(w, wh_slab, wl_slab, wsq);
    vq_mfma <<<512, 256, 0, stream>>>(z, wh_slab, wl_slab, wsq, out);
}